// Round 12
// baseline (274.539 us; speedup 1.0000x reference)
//
#include <hip/hip_runtime.h>

#define TSTEPS 15
#define HID    64
#define LAT    16
#define NBATCH 65536

typedef _Float16 v8h __attribute__((ext_vector_type(8)));
typedef _Float16 v4h __attribute__((ext_vector_type(4)));
typedef _Float16 v2h __attribute__((ext_vector_type(2)));
typedef float    v4f __attribute__((ext_vector_type(4)));

__device__ __forceinline__ float fast_sig(float x) {
    return __builtin_amdgcn_rcpf(1.0f + __expf(-x));
}
__device__ __forceinline__ float fast_tanh(float x) {
    return 2.0f * __builtin_amdgcn_rcpf(1.0f + __expf(-2.0f * x)) - 1.0f;
}

__device__ __forceinline__ v8h vzero8() {
    v8h v;
#pragma unroll
    for (int i = 0; i < 8; ++i) v[i] = (_Float16)0.0f;
    return v;
}

// v_cvt_pkrtz returns __fp16x2; bit-cast to our _Float16x2 (same bits).
__device__ __forceinline__ v4h pack4(float a, float b, float c, float d) {
    const v2h lo = __builtin_bit_cast(v2h, __builtin_amdgcn_cvt_pkrtz(a, b));
    const v2h hi = __builtin_bit_cast(v2h, __builtin_amdgcn_cvt_pkrtz(c, d));
    return __builtin_shufflevector(lo, hi, 0, 1, 2, 3);
}

// Software-pipelined fused 2-layer LSTM + FC.
// Round 12: 16 waves/block (1024 thr) x N=16 batch/wave -> 4 waves/SIMD.
// Rationale: at 2 waves/SIMD (rounds 8-11) VALUBusy plateaued at ~60% --
// 40% of cycles NO resident wave can issue (MFMA/LDS/trans latency). ILP
// attacks (dual-stream merge) bought only 6%; TLP is the remaining lever.
// Per-SIMD VALU work is unchanged (4x16 vs 2x32 elements); LDS total is
// unchanged (154624 B, state shrinks per-wave); live set ~115 regs fits
// the 128-reg budget 4 waves/SIMD mandates (waves_per_eu(4,4) pins it).
// Tripwire: VGPR_Count must be 128 (not 64) and WRITE_SIZE ~3.84 MB.
//
// LOAD-BEARING (round 7): without the per-iteration asm memory clobber,
// LICM hoists all A-fragment ds_reads (448 VGPRs worth) out of the t-loop
// -> forced scratch spill -> 3-4 GB HBM scratch traffic. DO NOT REMOVE.
//
// Merged steady-state body (one BB): L0(tt) + L1(tt-1), both consuming
// register-resident hf/gf from the previous iteration. Per-wave LDS state
// machine: write h0(tt) -> read hf -> write h1(tt-1) -> read gf -> FC.
//
//   D[m=gate(256), n=batch(16)] = A[weights] * B[z | h0 | x | h1]
// wf planes: 0=Wih0(z,K16; k=16 -> bias; rest 0) 1,2=Whh0 3,4=Wih1 5,6=Whh1.
// Gate order (PyTorch): 0=i,1=f,2=g,3=o ; g = 64*type + u, u=16a+4q+r;
// acc[ty] -> ty IS the gate type (mt = 4*ty+a).
__global__ __launch_bounds__(1024)
__attribute__((amdgpu_waves_per_eu(4, 4)))
void lstm2_pipe3(
        const float* __restrict__ z,
        const float* __restrict__ Wih0, const float* __restrict__ Whh0,
        const float* __restrict__ bih0, const float* __restrict__ bhh0,
        const float* __restrict__ Wih1, const float* __restrict__ Whh1,
        const float* __restrict__ bih1, const float* __restrict__ bhh1,
        const float* __restrict__ Wfc,  const float* __restrict__ bfc,
        float* __restrict__ out)
{
    __shared__ __align__(16) _Float16 wf[7 * 16 * 64 * 8];   // 114688 B
    __shared__ __align__(16) _Float16 wfcf[2 * 64 * 8];      //   2048 B
    __shared__ __align__(16) float    bsum1[256];            //   1024 B
    __shared__ __align__(16) _Float16 state[16][16 * 72];    //  36864 B
                                                             // 154624 B total

    const int tid  = threadIdx.x;
    const int wave = tid >> 6;           // 0..15
    const int lane = tid & 63;
    const int q    = lane >> 4;          // quad
    const int c    = lane & 15;          // batch col
    const int row0 = blockIdx.x * 256 + wave * 16;   // wave's batch base

    /* ---------------- one-time staging: weights + biases ----------------- */
#pragma unroll 2
    for (int e = tid; e < 7 * 16 * 64 * 8; e += 1024) {
        const int j  = e & 7;
        const int lm = (e >> 3) & 63;
        const int mt = (e >> 9) & 15;
        const int p  = e >> 13;                  // fragment plane 0..6
        const int g  = mt * 16 + (lm & 15);      // gate row 0..255
        const int kk = (lm >> 4) * 8 + j;        // k within 32-chunk
        float v;
        if (p == 0)      v = (kk < LAT) ? Wih0[g * LAT + kk]
                           : (kk == LAT ? bih0[g] + bhh0[g] : 0.0f);
        else if (p == 1) v = Whh0[g * HID + kk];
        else if (p == 2) v = Whh0[g * HID + 32 + kk];
        else if (p == 3) v = Wih1[g * HID + kk];
        else if (p == 4) v = Wih1[g * HID + 32 + kk];
        else if (p == 5) v = Whh1[g * HID + kk];
        else             v = Whh1[g * HID + 32 + kk];
        wf[e] = (_Float16)v;
    }
    // FC A-fragments: row m=0 carries Wfc, rows 1..15 zero
    if (tid < 2 * 64 * 8) {
        const int e  = tid;
        const int j  = e & 7;
        const int lm = (e >> 3) & 63;
        const int kc = e >> 9;
        const int kk = kc * 32 + (lm >> 4) * 8 + j;
        wfcf[e] = ((lm & 15) == 0) ? (_Float16)Wfc[kk] : (_Float16)0.0f;
    }
    if (tid < 256) bsum1[tid] = bih1[tid] + bhh1[tid];
    __syncthreads();   // the only barrier in the kernel

    _Float16* stW = &state[wave][0];
    const float bfcv = bfc[0];

    // z B-fragment (constant over t); element k=16 = 1.0 multiplies the
    // bias column staged in plane 0.
    v8h zfrag = vzero8();
    if (q < 2) {
        const float* zp = z + (size_t)(row0 + c) * LAT + q * 8;
        const float4 za = *(const float4*)(zp);
        const float4 zb = *(const float4*)(zp + 4);
        zfrag[0] = (_Float16)za.x; zfrag[1] = (_Float16)za.y;
        zfrag[2] = (_Float16)za.z; zfrag[3] = (_Float16)za.w;
        zfrag[4] = (_Float16)zb.x; zfrag[5] = (_Float16)zb.y;
        zfrag[6] = (_Float16)zb.z; zfrag[7] = (_Float16)zb.w;
    }
    if (q == 2) zfrag[0] = (_Float16)1.0f;   // bias slot

    v8h hf0 = vzero8(), hf1 = vzero8();   // h0/x B-frags (k-halves)
    v8h gf0 = vzero8(), gf1 = vzero8();   // h1 B-frags
    v4h h1pk[4];                          // packed h1 awaiting deferred write
    float c0s[16], c1s[16];
#pragma unroll
    for (int i = 0; i < 16; ++i) { c0s[i] = 0.0f; c1s[i] = 0.0f; }

#define AFRAG(pl, mt) (*(const v8h*)&wf[(((pl) * 16 + (mt)) * 64 + lane) * 8])
#define MFMA16(A, B, C) __builtin_amdgcn_mfma_f32_16x16x32_f16((A), (B), (C), 0, 0, 0)

    auto l0_part = [&]() {   // L0 MFMAs + epilogue + h0 stores (uses old hf)
#pragma unroll
        for (int a = 0; a < 4; ++a) {
            v4f acc0[4];
#pragma unroll
            for (int ty = 0; ty < 4; ++ty) {
                const int mt = 4 * ty + a;
                v4f t0 = {0.f, 0.f, 0.f, 0.f};
                t0 = MFMA16(AFRAG(0, mt), zfrag, t0);
                t0 = MFMA16(AFRAG(1, mt), hf0,   t0);
                t0 = MFMA16(AFRAG(2, mt), hf1,   t0);
                acc0[ty] = t0;
            }
            float hh[4];
#pragma unroll
            for (int r = 0; r < 4; ++r) {
                const float ig = fast_sig(acc0[0][r]);
                const float fg = fast_sig(acc0[1][r]);
                const float gg = fast_tanh(acc0[2][r]);
                const float og = fast_sig(acc0[3][r]);
                const float cc = fg * c0s[a * 4 + r] + ig * gg;
                c0s[a * 4 + r] = cc;
                hh[r] = og * fast_tanh(cc);
            }
            *(v4h*)&stW[c * 72 + 16 * a + 4 * q] = pack4(hh[0], hh[1], hh[2], hh[3]);
        }
    };

    auto l1_part = [&]() {   // L1 MFMAs + epilogue -> h1pk (uses old hf, gf)
#pragma unroll
        for (int a = 0; a < 4; ++a) {
            v4f acc1[4];
#pragma unroll
            for (int ty = 0; ty < 4; ++ty) {
                const int mt = 4 * ty + a;
                v4f t0 = *(const v4f*)&bsum1[64 * ty + 16 * a + 4 * q];
                t0 = MFMA16(AFRAG(3, mt), hf0, t0);
                t0 = MFMA16(AFRAG(4, mt), hf1, t0);
                t0 = MFMA16(AFRAG(5, mt), gf0, t0);
                t0 = MFMA16(AFRAG(6, mt), gf1, t0);
                acc1[ty] = t0;
            }
            float hh[4];
#pragma unroll
            for (int r = 0; r < 4; ++r) {
                const float ig = fast_sig(acc1[0][r]);
                const float fg = fast_sig(acc1[1][r]);
                const float gg = fast_tanh(acc1[2][r]);
                const float og = fast_sig(acc1[3][r]);
                const float cc = fg * c1s[a * 4 + r] + ig * gg;
                c1s[a * 4 + r] = cc;
                hh[r] = og * fast_tanh(cc);
            }
            h1pk[a] = pack4(hh[0], hh[1], hh[2], hh[3]);
        }
    };

    auto l0_finish = [&]() {   // pull new h0 into B-frag registers
        hf0 = *(const v8h*)&stW[c * 72 + 8 * q];
        hf1 = *(const v8h*)&stW[c * 72 + 32 + 8 * q];
    };

    auto l1_finish = [&](int trow) {   // h1 store, gf reload, FC, out
#pragma unroll
        for (int a = 0; a < 4; ++a)
            *(v4h*)&stW[c * 72 + 16 * a + 4 * q] = h1pk[a];
        gf0 = *(const v8h*)&stW[c * 72 + 8 * q];
        gf1 = *(const v8h*)&stW[c * 72 + 32 + 8 * q];
        const v8h w0 = *(const v8h*)&wfcf[(0 * 64 + lane) * 8];
        const v8h w1 = *(const v8h*)&wfcf[(1 * 64 + lane) * 8];
        v4f f = {0.f, 0.f, 0.f, 0.f};
        f = MFMA16(w0, gf0, f);
        f = MFMA16(w1, gf1, f);
        if (lane < 16)
            out[(size_t)(row0 + lane) * TSTEPS + trow] = f[0] + bfcv;
    };

    /* --------------------------- pipeline --------------------------- */
    l0_part();          // L0 step 0 (hf, gf are zero)
    l0_finish();

#pragma unroll 1
    for (int tt = 1; tt < TSTEPS; ++tt) {
        // Kill LICM (see header comment). Emits no instructions.
        __asm__ __volatile__("" ::: "memory");
        l0_part();           // writes h0(tt) to stW
        l1_part();           // -> h1pk (registers only)
        l0_finish();         // hf <- h0(tt)
        l1_finish(tt - 1);   // h1 store, gf <- h1(tt-1), FC, out row tt-1
    }

    __asm__ __volatile__("" ::: "memory");
    l1_part();          // L1 step 14
    l1_finish(TSTEPS - 1);

#undef AFRAG
#undef MFMA16
}

extern "C" void kernel_launch(void* const* d_in, const int* in_sizes, int n_in,
                              void* d_out, int out_size, void* d_ws, size_t ws_size,
                              hipStream_t stream)
{
    (void)in_sizes; (void)n_in; (void)out_size; (void)d_ws; (void)ws_size;

    const float* z    = (const float*)d_in[0];
    const float* Wih0 = (const float*)d_in[1];
    const float* Whh0 = (const float*)d_in[2];
    const float* bih0 = (const float*)d_in[3];
    const float* bhh0 = (const float*)d_in[4];
    const float* Wih1 = (const float*)d_in[5];
    const float* Whh1 = (const float*)d_in[6];
    const float* bih1 = (const float*)d_in[7];
    const float* bhh1 = (const float*)d_in[8];
    const float* Wfc  = (const float*)d_in[9];
    const float* bfc  = (const float*)d_in[10];

    lstm2_pipe3<<<dim3(NBATCH / 256), dim3(1024), 0, stream>>>(
        z, Wih0, Whh0, bih0, bhh0, Wih1, Whh1, bih1, bhh1, Wfc, bfc,
        (float*)d_out);
}

// Round 13
// 249.419 us; speedup vs baseline: 1.1007x; 1.1007x over previous
//
#include <hip/hip_runtime.h>

#define TSTEPS 15
#define HID    64
#define LAT    16
#define NBATCH 65536
#define LOG2E  1.44269504088896f

typedef _Float16 v8h __attribute__((ext_vector_type(8)));
typedef _Float16 v4h __attribute__((ext_vector_type(4)));
typedef _Float16 v2h __attribute__((ext_vector_type(2)));
typedef float    v4f __attribute__((ext_vector_type(4)));

__device__ __forceinline__ v8h vzero8() {
    v8h v;
#pragma unroll
    for (int i = 0; i < 8; ++i) v[i] = (_Float16)0.0f;
    return v;
}

// v_cvt_pkrtz returns __fp16x2; bit-cast to our _Float16x2 (same bits).
__device__ __forceinline__ v4h pack4(float a, float b, float c, float d) {
    const v2h lo = __builtin_bit_cast(v2h, __builtin_amdgcn_cvt_pkrtz(a, b));
    const v2h hi = __builtin_bit_cast(v2h, __builtin_amdgcn_cvt_pkrtz(c, d));
    return __builtin_shufflevector(lo, hi, 0, 1, 2, 3);
}

// LSTM cell update with shared-rcp activations. Gate pre-acts ai/af/ag/ao
// arrive PRE-SCALED by log2e (folded into staged weights/biases), so
// exp2(-x) needs no multiply (neg is a free src modifier).
//   sig(a)*tanh(b) = (1-e2)*rcp((1+e1)(1+e2)),  e1=exp2(-a'), e2=exp2(-2b')
// 4 exp2 + 2 rcp per unit (was 5 exp + 5 rcp).
__device__ __forceinline__ float cell_update(float ai, float af, float ag,
                                             float ao, float& cst) {
    const float ei = __builtin_amdgcn_exp2f(-ai);
    const float ef = __builtin_amdgcn_exp2f(-af);
    const float eg = __builtin_amdgcn_exp2f(-2.0f * ag);
    const float eo = __builtin_amdgcn_exp2f(-ao);
    const float ig = (1.0f - eg) *
        __builtin_amdgcn_rcpf((1.0f + ei) * (1.0f + eg));      // i*g
    const float f  = __builtin_amdgcn_rcpf(1.0f + ef);          // forget gate
    const float cc = fmaf(f, cst, ig);
    cst = cc;
    const float ec = __builtin_amdgcn_exp2f(cc * (-2.0f * LOG2E));  // true scale
    return (1.0f - ec) *
        __builtin_amdgcn_rcpf((1.0f + eo) * (1.0f + ec));      // o*tanh(c)
}

// Software-pipelined fused 2-layer LSTM + FC.
// 16 waves/block (1024 thr) x N=16 batch/wave -> 4 waves/SIMD; at this
// occupancy the 128-reg unified budget splits 64 VGPR + 64 AGPR (r12:
// VGPR_Count=64 with only ~2 MB accvgpr-side traffic -- benign, not the
// r3/r4 spill storm).
//
// LOAD-BEARING (round 7): without the per-iteration asm memory clobber,
// LICM hoists all A-fragment ds_reads (448 VGPRs worth) out of the t-loop
// -> forced scratch spill -> 3-4 GB HBM scratch traffic. DO NOT REMOVE.
// (Pre-loop register loads are SSA values and survive the clobber.)
//
// Round 13: transcendental diet (10 -> 6 quarter-rate ops/unit) via
// shared-rcp pairing + log2e pre-scaled weights; FC fragments hoisted.
//
// Merged steady-state body (one BB): L0(tt) + L1(tt-1). Per-wave LDS
// state machine: write h0(tt) -> read hf -> write h1(tt-1) -> read gf -> FC.
//
//   D[m=gate(256), n=batch(16)] = A[weights*log2e] * B[z | h0 | x | h1]
// wf planes: 0=Wih0(z,K16; k=16 -> bias; rest 0) 1,2=Whh0 3,4=Wih1 5,6=Whh1.
// Gate order (PyTorch): 0=i,1=f,2=g,3=o ; g = 64*type + u, u=16a+4q+r;
// acc[ty] -> ty IS the gate type (mt = 4*ty+a).
__global__ __launch_bounds__(1024)
__attribute__((amdgpu_waves_per_eu(4, 4)))
void lstm2_pipe4(
        const float* __restrict__ z,
        const float* __restrict__ Wih0, const float* __restrict__ Whh0,
        const float* __restrict__ bih0, const float* __restrict__ bhh0,
        const float* __restrict__ Wih1, const float* __restrict__ Whh1,
        const float* __restrict__ bih1, const float* __restrict__ bhh1,
        const float* __restrict__ Wfc,  const float* __restrict__ bfc,
        float* __restrict__ out)
{
    __shared__ __align__(16) _Float16 wf[7 * 16 * 64 * 8];   // 114688 B
    __shared__ __align__(16) _Float16 wfcf[2 * 64 * 8];      //   2048 B
    __shared__ __align__(16) float    bsum1[256];            //   1024 B
    __shared__ __align__(16) _Float16 state[16][16 * 72];    //  36864 B
                                                             // 154624 B total

    const int tid  = threadIdx.x;
    const int wave = tid >> 6;           // 0..15
    const int lane = tid & 63;
    const int q    = lane >> 4;          // quad
    const int c    = lane & 15;          // batch col
    const int row0 = blockIdx.x * 256 + wave * 16;   // wave's batch base

    /* ------- one-time staging: weights + biases, all scaled by log2e ----- */
#pragma unroll 2
    for (int e = tid; e < 7 * 16 * 64 * 8; e += 1024) {
        const int j  = e & 7;
        const int lm = (e >> 3) & 63;
        const int mt = (e >> 9) & 15;
        const int p  = e >> 13;                  // fragment plane 0..6
        const int g  = mt * 16 + (lm & 15);      // gate row 0..255
        const int kk = (lm >> 4) * 8 + j;        // k within 32-chunk
        float v;
        if (p == 0)      v = (kk < LAT) ? Wih0[g * LAT + kk]
                           : (kk == LAT ? bih0[g] + bhh0[g] : 0.0f);
        else if (p == 1) v = Whh0[g * HID + kk];
        else if (p == 2) v = Whh0[g * HID + 32 + kk];
        else if (p == 3) v = Wih1[g * HID + kk];
        else if (p == 4) v = Wih1[g * HID + 32 + kk];
        else if (p == 5) v = Whh1[g * HID + kk];
        else             v = Whh1[g * HID + 32 + kk];
        wf[e] = (_Float16)(v * LOG2E);
    }
    // FC A-fragments: row m=0 carries Wfc (TRUE scale), rows 1..15 zero
    if (tid < 2 * 64 * 8) {
        const int e  = tid;
        const int j  = e & 7;
        const int lm = (e >> 3) & 63;
        const int kc = e >> 9;
        const int kk = kc * 32 + (lm >> 4) * 8 + j;
        wfcf[e] = ((lm & 15) == 0) ? (_Float16)Wfc[kk] : (_Float16)0.0f;
    }
    if (tid < 256) bsum1[tid] = (bih1[tid] + bhh1[tid]) * LOG2E;
    __syncthreads();   // the only barrier in the kernel

    _Float16* stW = &state[wave][0];
    const float bfcv = bfc[0];

    // FC fragments hoisted (SSA regs survive the clobber)
    const v8h wfc0 = *(const v8h*)&wfcf[(0 * 64 + lane) * 8];
    const v8h wfc1 = *(const v8h*)&wfcf[(1 * 64 + lane) * 8];

    // z B-fragment (constant over t); element k=16 = 1.0 multiplies the
    // (log2e-scaled) bias column staged in plane 0.
    v8h zfrag = vzero8();
    if (q < 2) {
        const float* zp = z + (size_t)(row0 + c) * LAT + q * 8;
        const float4 za = *(const float4*)(zp);
        const float4 zb = *(const float4*)(zp + 4);
        zfrag[0] = (_Float16)za.x; zfrag[1] = (_Float16)za.y;
        zfrag[2] = (_Float16)za.z; zfrag[3] = (_Float16)za.w;
        zfrag[4] = (_Float16)zb.x; zfrag[5] = (_Float16)zb.y;
        zfrag[6] = (_Float16)zb.z; zfrag[7] = (_Float16)zb.w;
    }
    if (q == 2) zfrag[0] = (_Float16)1.0f;   // bias slot

    v8h hf0 = vzero8(), hf1 = vzero8();   // h0/x B-frags (k-halves)
    v8h gf0 = vzero8(), gf1 = vzero8();   // h1 B-frags
    v4h h1pk[4];                          // packed h1 awaiting deferred write
    float c0s[16], c1s[16];
#pragma unroll
    for (int i = 0; i < 16; ++i) { c0s[i] = 0.0f; c1s[i] = 0.0f; }

#define AFRAG(pl, mt) (*(const v8h*)&wf[(((pl) * 16 + (mt)) * 64 + lane) * 8])
#define MFMA16(A, B, C) __builtin_amdgcn_mfma_f32_16x16x32_f16((A), (B), (C), 0, 0, 0)

    auto l0_part = [&]() {   // L0 MFMAs + epilogue + h0 stores (uses old hf)
#pragma unroll
        for (int a = 0; a < 4; ++a) {
            v4f acc0[4];
#pragma unroll
            for (int ty = 0; ty < 4; ++ty) {
                const int mt = 4 * ty + a;
                v4f t0 = {0.f, 0.f, 0.f, 0.f};
                t0 = MFMA16(AFRAG(0, mt), zfrag, t0);
                t0 = MFMA16(AFRAG(1, mt), hf0,   t0);
                t0 = MFMA16(AFRAG(2, mt), hf1,   t0);
                acc0[ty] = t0;
            }
            float hh[4];
#pragma unroll
            for (int r = 0; r < 4; ++r)
                hh[r] = cell_update(acc0[0][r], acc0[1][r], acc0[2][r],
                                    acc0[3][r], c0s[a * 4 + r]);
            *(v4h*)&stW[c * 72 + 16 * a + 4 * q] = pack4(hh[0], hh[1], hh[2], hh[3]);
        }
    };

    auto l1_part = [&]() {   // L1 MFMAs + epilogue -> h1pk (uses old hf, gf)
#pragma unroll
        for (int a = 0; a < 4; ++a) {
            v4f acc1[4];
#pragma unroll
            for (int ty = 0; ty < 4; ++ty) {
                const int mt = 4 * ty + a;
                v4f t0 = *(const v4f*)&bsum1[64 * ty + 16 * a + 4 * q];
                t0 = MFMA16(AFRAG(3, mt), hf0, t0);
                t0 = MFMA16(AFRAG(4, mt), hf1, t0);
                t0 = MFMA16(AFRAG(5, mt), gf0, t0);
                t0 = MFMA16(AFRAG(6, mt), gf1, t0);
                acc1[ty] = t0;
            }
            float hh[4];
#pragma unroll
            for (int r = 0; r < 4; ++r)
                hh[r] = cell_update(acc1[0][r], acc1[1][r], acc1[2][r],
                                    acc1[3][r], c1s[a * 4 + r]);
            h1pk[a] = pack4(hh[0], hh[1], hh[2], hh[3]);
        }
    };

    auto l0_finish = [&]() {   // pull new h0 into B-frag registers
        hf0 = *(const v8h*)&stW[c * 72 + 8 * q];
        hf1 = *(const v8h*)&stW[c * 72 + 32 + 8 * q];
    };

    auto l1_finish = [&](int trow) {   // h1 store, gf reload, FC, out
#pragma unroll
        for (int a = 0; a < 4; ++a)
            *(v4h*)&stW[c * 72 + 16 * a + 4 * q] = h1pk[a];
        gf0 = *(const v8h*)&stW[c * 72 + 8 * q];
        gf1 = *(const v8h*)&stW[c * 72 + 32 + 8 * q];
        v4f f = {0.f, 0.f, 0.f, 0.f};
        f = MFMA16(wfc0, gf0, f);
        f = MFMA16(wfc1, gf1, f);
        if (lane < 16)
            out[(size_t)(row0 + lane) * TSTEPS + trow] = f[0] + bfcv;
    };

    /* --------------------------- pipeline --------------------------- */
    l0_part();          // L0 step 0 (hf, gf are zero)
    l0_finish();

#pragma unroll 1
    for (int tt = 1; tt < TSTEPS; ++tt) {
        // Kill LICM (see header comment). Emits no instructions.
        __asm__ __volatile__("" ::: "memory");
        l0_part();           // writes h0(tt) to stW
        l1_part();           // -> h1pk (registers only)
        l0_finish();         // hf <- h0(tt)
        l1_finish(tt - 1);   // h1 store, gf <- h1(tt-1), FC, out row tt-1
    }

    __asm__ __volatile__("" ::: "memory");
    l1_part();          // L1 step 14
    l1_finish(TSTEPS - 1);

#undef AFRAG
#undef MFMA16
}

extern "C" void kernel_launch(void* const* d_in, const int* in_sizes, int n_in,
                              void* d_out, int out_size, void* d_ws, size_t ws_size,
                              hipStream_t stream)
{
    (void)in_sizes; (void)n_in; (void)out_size; (void)d_ws; (void)ws_size;

    const float* z    = (const float*)d_in[0];
    const float* Wih0 = (const float*)d_in[1];
    const float* Whh0 = (const float*)d_in[2];
    const float* bih0 = (const float*)d_in[3];
    const float* bhh0 = (const float*)d_in[4];
    const float* Wih1 = (const float*)d_in[5];
    const float* Whh1 = (const float*)d_in[6];
    const float* bih1 = (const float*)d_in[7];
    const float* bhh1 = (const float*)d_in[8];
    const float* Wfc  = (const float*)d_in[9];
    const float* bfc  = (const float*)d_in[10];

    lstm2_pipe4<<<dim3(NBATCH / 256), dim3(1024), 0, stream>>>(
        z, Wih0, Whh0, bih0, bhh0, Wih1, Whh1, bih1, bhh1, Wfc, bfc,
        (float*)d_out);
}